// Round 16
// baseline (1084.789 us; speedup 1.0000x reference)
//
#include <hip/hip_runtime.h>

#define T_LEN 2048
#define HID 64
#define EMB 128
#define WD 16                // steps per window (barrier period) — R16: 8->16
#define NWIN (T_LEN / WD)    // 128
#define NPH (NWIN + 4)       // +4 windows of pipeline lag (C2)

typedef _Float16 half2_t __attribute__((ext_vector_type(2)));
typedef unsigned uint4v __attribute__((ext_vector_type(4)));

#if __has_builtin(__builtin_amdgcn_exp2f)
#define EXP2F(x) __builtin_amdgcn_exp2f(x)
#else
#define EXP2F(x) exp2f(x)
#endif
#if __has_builtin(__builtin_amdgcn_rcpf)
#define RCPF(x) __builtin_amdgcn_rcpf(x)
#else
#define RCPF(x) (1.0f / (x))
#endif

#define LOG2E 1.4426950408889634f

__device__ __forceinline__ float fdot2(unsigned a, unsigned b, float c) {
    return __builtin_amdgcn_fdot2(__builtin_bit_cast(half2_t, a),
                                  __builtin_bit_cast(half2_t, b), c, false);
}

// Full-row 64-MAC dot: 8 weight quads vs 8 gathered-h quads, 4 chains.
__device__ __forceinline__ float dotrow(const uint4v* w, const uint4v* g, float init) {
    float a0 = init, a1 = 0.f, a2 = 0.f, a3 = 0.f;
    #pragma unroll
    for (int q = 0; q < 8; ++q) {
        a0 = fdot2(w[q][0], g[q][0], a0);
        a1 = fdot2(w[q][1], g[q][1], a1);
        a2 = fdot2(w[q][2], g[q][2], a2);
        a3 = fdot2(w[q][3], g[q][3], a3);
    }
    return (a0 + a1) + (a2 + a3);
}

__device__ __forceinline__ uint4v pack8(float4 a, float4 b, float s) {
    half2_t h0{(_Float16)(a.x * s), (_Float16)(a.y * s)};
    half2_t h1{(_Float16)(a.z * s), (_Float16)(a.w * s)};
    half2_t h2{(_Float16)(b.x * s), (_Float16)(b.y * s)};
    half2_t h3{(_Float16)(b.z * s), (_Float16)(b.w * s)};
    uint4v q;
    q[0] = __builtin_bit_cast(unsigned, h0);
    q[1] = __builtin_bit_cast(unsigned, h1);
    q[2] = __builtin_bit_cast(unsigned, h2);
    q[3] = __builtin_bit_cast(unsigned, h3);
    return q;
}

// One 64-float weight row -> 8 packed quads, exp2-space prescaled.
__device__ __forceinline__ void cvt8(const float* __restrict__ Wp, float s, uint4v* dst) {
    const float4* p = reinterpret_cast<const float4*>(Wp);
    #pragma unroll
    for (int k = 0; k < 8; ++k) dst[k] = pack8(p[2 * k], p[2 * k + 1], s);
}

// ROUND 16 = ROUND 15 with WD 8 -> 16: barrier every 16 steps (130 barriers
// vs 260). R15 decomposition: wall 1190 cyc/step = 640 dot floor + ~320 busy
// overhead + ~225 barrier idle; this halves the last term. All parity/slack
// logic is WD-independent. j-loops at unroll 8 keep per-pass code size at
// R15's proven level (I-cache guard).
// Roles (R15, SIMD-balanced at 4 waves x 2/SIMD, all SIMDs = 5120 dot-cyc
// per 8 steps):
//   wv0/1/2 = C0/C1/C2 (4 whh rows, in-lane gates, scalar cell)  [S0/S1/S2]
//   wv4 = wih1_i, wv5 = wih1_f, wv6 = wih1_g (1 row each)        [S0/S1/S2]
//   wv3 = wih1_o + wih2_i (2 rows)                               [S3]
//   wv7 = wih2_{f,g,o}    (3 rows)                               [S3]
// Schedule: phase ph: C0 h0-window ph | p1 for window ph-1 | C1 h1 window
// ph-2 | p2 for window ph-3 | C2 h2 window ph-4. One barrier/phase. Within a
// window C waves recurse privately (same-wave lgkmcnt ordering).
__global__ __launch_bounds__(512)
__attribute__((amdgpu_waves_per_eu(2, 2)))
void lstm3_fused(
    const float* __restrict__ x,
    const float* __restrict__ Wih0, const float* __restrict__ Whh0,
    const float* __restrict__ bih0, const float* __restrict__ bhh0,
    const float* __restrict__ Wih1, const float* __restrict__ Whh1,
    const float* __restrict__ bih1, const float* __restrict__ bhh1,
    const float* __restrict__ Wih2, const float* __restrict__ Whh2,
    const float* __restrict__ bih2, const float* __restrict__ bhh2,
    const float* __restrict__ fcW,  const float* __restrict__ fcb,
    float* __restrict__ out)
{
    const int b   = blockIdx.x;
    const int tid = threadIdx.x;
    const int wv  = tid >> 6;          // 0..7 (wave-uniform role)
    const int L   = tid & 63;          // owned h-index / row-lane

    __shared__ __align__(16) _Float16 h0ring[2 * WD][HID];  // 2 windows of h0
    __shared__ __align__(16) _Float16 h1ring[2 * WD][HID];  // 2 windows of h1
    __shared__ __align__(16) _Float16 h2ring[2][HID];       // h2 self-ring
    __shared__ float p1buf[2][WD][4][HID];                  // wih1 partials
    __shared__ float p2buf[2][WD][4][HID];                  // wih2 partials
    __shared__ __align__(16) float xs[T_LEN];

    // Stage x[b,0,:] (512 float4 by 512 threads); zero the rings.
    {
        const float4* xg4 = reinterpret_cast<const float4*>(x + b * T_LEN);
        reinterpret_cast<float4*>(xs)[tid] = xg4[tid];
        reinterpret_cast<unsigned*>(h0ring)[tid] = 0u;      // 512 dwords
        reinterpret_cast<unsigned*>(h0ring)[tid + 512] = 0u;
        reinterpret_cast<unsigned*>(h1ring)[tid] = 0u;
        reinterpret_cast<unsigned*>(h1ring)[tid + 512] = 0u;
        if (tid < 64) reinterpret_cast<unsigned*>(h2ring)[tid] = 0u;
    }

    const float sI = -LOG2E, sF = -LOG2E, sG = -2.f * LOG2E, sO = -LOG2E;
    const float scl[4] = {sI, sF, sG, sO};

    uint4v w[4][8];                    // C: 4 whh rows; wv3: 2; wv7: 3
    float bias4[4] = {0.f, 0.f, 0.f, 0.f};
    float wx4[4]   = {0.f, 0.f, 0.f, 0.f};

    if (wv < 3) {                      // C_l: whh_l all 4 gate rows
        const float* Wh = (wv == 0) ? Whh0 : (wv == 1) ? Whh1 : Whh2;
        const float* bi = (wv == 0) ? bih0 : (wv == 1) ? bih1 : bih2;
        const float* bh = (wv == 0) ? bhh0 : (wv == 1) ? bhh1 : bhh2;
        #pragma unroll
        for (int c = 0; c < 4; ++c) {
            cvt8(Wh + (c * 64 + L) * 64, scl[c], w[c]);
            bias4[c] = (bi[c * 64 + L] + bh[c * 64 + L]) * scl[c];
        }
        if (wv == 0) {
            #pragma unroll
            for (int c = 0; c < 4; ++c) wx4[c] = Wih0[c * 64 + L] * scl[c];
        }
    } else if (wv == 4) {              // P: wih1_i
        cvt8(Wih1 + (  0 + L) * 64, sI, w[0]);
    } else if (wv == 5) {              // P: wih1_f
        cvt8(Wih1 + ( 64 + L) * 64, sF, w[0]);
    } else if (wv == 6) {              // P: wih1_g
        cvt8(Wih1 + (128 + L) * 64, sG, w[0]);
    } else if (wv == 3) {              // P: wih1_o + wih2_i
        cvt8(Wih1 + (192 + L) * 64, sO, w[0]);
        cvt8(Wih2 + (  0 + L) * 64, sI, w[1]);
    } else {                           // wv == 7: wih2_{f,g,o}
        cvt8(Wih2 + ( 64 + L) * 64, sF, w[0]);
        cvt8(Wih2 + (128 + L) * 64, sG, w[1]);
        cvt8(Wih2 + (192 + L) * 64, sO, w[2]);
    }

    float cst = 0.f;                   // cell state (C waves, lane-local)
    __syncthreads();

    for (int ph = 0; ph < NPH; ++ph) {
        const int par = ph & 1;

        if (wv == 0) {
            if (ph < NWIN) {           // h0 window ph
                _Float16* cur = &h0ring[par * WD][0];
                const _Float16* prv = &h0ring[(par ^ 1) * WD][0];
                const int tb = ph * WD;
                #pragma unroll 8
                for (int j = 0; j < WD; ++j) {
                    const uint4v* hp = reinterpret_cast<const uint4v*>(
                        (j == 0) ? (prv + (WD - 1) * HID) : (cur + (j - 1) * HID));
                    uint4v g[8];
                    #pragma unroll
                    for (int k = 0; k < 8; ++k) g[k] = hp[k];
                    float xv = xs[tb + j];
                    float d0 = dotrow(w[0], g, fmaf(wx4[0], xv, bias4[0]));
                    float d1 = dotrow(w[1], g, fmaf(wx4[1], xv, bias4[1]));
                    float d2 = dotrow(w[2], g, fmaf(wx4[2], xv, bias4[2]));
                    float d3 = dotrow(w[3], g, fmaf(wx4[3], xv, bias4[3]));
                    float ai = RCPF(1.f + EXP2F(d0));
                    float af = RCPF(1.f + EXP2F(d1));
                    float ag = fmaf(2.f, RCPF(1.f + EXP2F(d2)), -1.f);
                    float ao = RCPF(1.f + EXP2F(d3));
                    cst = fmaf(af, cst, ai * ag);
                    float tc = fmaf(2.f, RCPF(1.f + EXP2F(-2.f * LOG2E * cst)), -1.f);
                    cur[j * HID + L] = (_Float16)(ao * tc);
                }
            }
        } else if (wv == 1) {
            if (ph >= 2 && ph < NWIN + 2) {    // h1 window ph-2 (p1[par] ready)
                _Float16* cur = &h1ring[par * WD][0];
                const _Float16* prv = &h1ring[(par ^ 1) * WD][0];
                const float (*pb)[4][HID] = p1buf[par];
                #pragma unroll 8
                for (int j = 0; j < WD; ++j) {
                    const uint4v* hp = reinterpret_cast<const uint4v*>(
                        (j == 0) ? (prv + (WD - 1) * HID) : (cur + (j - 1) * HID));
                    uint4v g[8];
                    #pragma unroll
                    for (int k = 0; k < 8; ++k) g[k] = hp[k];
                    float d0 = dotrow(w[0], g, bias4[0] + pb[j][0][L]);
                    float d1 = dotrow(w[1], g, bias4[1] + pb[j][1][L]);
                    float d2 = dotrow(w[2], g, bias4[2] + pb[j][2][L]);
                    float d3 = dotrow(w[3], g, bias4[3] + pb[j][3][L]);
                    float ai = RCPF(1.f + EXP2F(d0));
                    float af = RCPF(1.f + EXP2F(d1));
                    float ag = fmaf(2.f, RCPF(1.f + EXP2F(d2)), -1.f);
                    float ao = RCPF(1.f + EXP2F(d3));
                    cst = fmaf(af, cst, ai * ag);
                    float tc = fmaf(2.f, RCPF(1.f + EXP2F(-2.f * LOG2E * cst)), -1.f);
                    cur[j * HID + L] = (_Float16)(ao * tc);
                }
            }
        } else if (wv == 2) {
            if (ph >= 4) {                     // h2 window ph-4 (p2[par] ready)
                const float (*pb)[4][HID] = p2buf[par];
                #pragma unroll 8
                for (int j = 0; j < WD; ++j) {
                    const uint4v* hp = reinterpret_cast<const uint4v*>(
                        &h2ring[(j & 1) ^ 1][0]);
                    uint4v g[8];
                    #pragma unroll
                    for (int k = 0; k < 8; ++k) g[k] = hp[k];
                    float d0 = dotrow(w[0], g, bias4[0] + pb[j][0][L]);
                    float d1 = dotrow(w[1], g, bias4[1] + pb[j][1][L]);
                    float d2 = dotrow(w[2], g, bias4[2] + pb[j][2][L]);
                    float d3 = dotrow(w[3], g, bias4[3] + pb[j][3][L]);
                    float ai = RCPF(1.f + EXP2F(d0));
                    float af = RCPF(1.f + EXP2F(d1));
                    float ag = fmaf(2.f, RCPF(1.f + EXP2F(d2)), -1.f);
                    float ao = RCPF(1.f + EXP2F(d3));
                    cst = fmaf(af, cst, ai * ag);
                    float tc = fmaf(2.f, RCPF(1.f + EXP2F(-2.f * LOG2E * cst)), -1.f);
                    h2ring[j & 1][L] = (_Float16)(ao * tc);
                }
            }
        } else {
            // Producer roles. p1 active: ph in [1, NWIN]; p2: ph in [3, NWIN+2].
            const bool p1act = (ph >= 1 && ph < NWIN + 1);
            const bool p2act = (ph >= 3 && ph < NWIN + 3);
            if (wv == 4 || wv == 5 || wv == 6) {
                if (p1act) {                   // one wih1 row vs h0 window ph-1
                    const _Float16* hw = &h0ring[(par ^ 1) * WD][0];
                    float (*po)[4][HID] = p1buf[par ^ 1];
                    const int c0 = wv - 4;     // 4->i(0), 5->f(1), 6->g(2)
                    #pragma unroll 8
                    for (int j = 0; j < WD; ++j) {
                        const uint4v* hp = reinterpret_cast<const uint4v*>(hw + j * HID);
                        uint4v g[8];
                        #pragma unroll
                        for (int k = 0; k < 8; ++k) g[k] = hp[k];
                        po[j][c0][L] = dotrow(w[0], g, 0.f);
                    }
                }
            } else if (wv == 3) {
                if (p1act) {                   // wih1_o vs h0 window ph-1
                    const _Float16* hw = &h0ring[(par ^ 1) * WD][0];
                    float (*po)[4][HID] = p1buf[par ^ 1];
                    #pragma unroll 8
                    for (int j = 0; j < WD; ++j) {
                        const uint4v* hp = reinterpret_cast<const uint4v*>(hw + j * HID);
                        uint4v g[8];
                        #pragma unroll
                        for (int k = 0; k < 8; ++k) g[k] = hp[k];
                        po[j][3][L] = dotrow(w[0], g, 0.f);
                    }
                }
                if (p2act) {                   // wih2_i vs h1 window ph-3
                    const _Float16* hw = &h1ring[(par ^ 1) * WD][0];
                    float (*po)[4][HID] = p2buf[par ^ 1];
                    #pragma unroll 8
                    for (int j = 0; j < WD; ++j) {
                        const uint4v* hp = reinterpret_cast<const uint4v*>(hw + j * HID);
                        uint4v g[8];
                        #pragma unroll
                        for (int k = 0; k < 8; ++k) g[k] = hp[k];
                        po[j][0][L] = dotrow(w[1], g, 0.f);
                    }
                }
            } else {                           // wv == 7: wih2_{f,g,o}
                if (p2act) {
                    const _Float16* hw = &h1ring[(par ^ 1) * WD][0];
                    float (*po)[4][HID] = p2buf[par ^ 1];
                    #pragma unroll 4
                    for (int j = 0; j < WD; ++j) {
                        const uint4v* hp = reinterpret_cast<const uint4v*>(hw + j * HID);
                        uint4v g[8];
                        #pragma unroll
                        for (int k = 0; k < 8; ++k) g[k] = hp[k];
                        po[j][1][L] = dotrow(w[0], g, 0.f);
                        po[j][2][L] = dotrow(w[1], g, 0.f);
                        po[j][3][L] = dotrow(w[2], g, 0.f);
                    }
                }
            }
        }

        __syncthreads();   // publish window: h rings + p-buffers
    }

    // Final FC (f32): h2[2047] -> window step 15 -> slot 15&1 = 1.
    if (tid < EMB) {
        float acc = fcb[tid];
        const _Float16* hf = &h2ring[1][0];
        const float4* W4 = reinterpret_cast<const float4*>(fcW + tid * HID);
        #pragma unroll
        for (int k = 0; k < 16; ++k) {
            float4 wv4 = W4[k];
            acc = fmaf(wv4.x, (float)hf[4 * k + 0], acc);
            acc = fmaf(wv4.y, (float)hf[4 * k + 1], acc);
            acc = fmaf(wv4.z, (float)hf[4 * k + 2], acc);
            acc = fmaf(wv4.w, (float)hf[4 * k + 3], acc);
        }
        out[b * EMB + tid] = acc;
    }
}

extern "C" void kernel_launch(void* const* d_in, const int* in_sizes, int n_in,
                              void* d_out, int out_size, void* d_ws, size_t ws_size,
                              hipStream_t stream) {
    const float* x    = (const float*)d_in[0];
    const float* Wih0 = (const float*)d_in[1];
    const float* Whh0 = (const float*)d_in[2];
    const float* bih0 = (const float*)d_in[3];
    const float* bhh0 = (const float*)d_in[4];
    const float* Wih1 = (const float*)d_in[5];
    const float* Whh1 = (const float*)d_in[6];
    const float* bih1 = (const float*)d_in[7];
    const float* bhh1 = (const float*)d_in[8];
    const float* Wih2 = (const float*)d_in[9];
    const float* Whh2 = (const float*)d_in[10];
    const float* bih2 = (const float*)d_in[11];
    const float* bhh2 = (const float*)d_in[12];
    const float* fcW  = (const float*)d_in[13];
    const float* fcb  = (const float*)d_in[14];
    float* out = (float*)d_out;

    lstm3_fused<<<dim3(256), dim3(512), 0, stream>>>(
        x, Wih0, Whh0, bih0, bhh0,
        Wih1, Whh1, bih1, bhh1,
        Wih2, Whh2, bih2, bhh2,
        fcW, fcb, out);
}

// Round 17
// 1026.553 us; speedup vs baseline: 1.0567x; 1.0567x over previous
//
#include <hip/hip_runtime.h>

#define T_LEN 2048
#define HID 64
#define EMB 128
#define WD 8                 // steps per window (R16 showed 16 regresses)
#define NWIN (T_LEN / WD)    // 256
#define NPH (NWIN + 4)       // +4 windows of pipeline lag (C2)

typedef _Float16 half2_t __attribute__((ext_vector_type(2)));
typedef unsigned uint4v __attribute__((ext_vector_type(4)));

#if __has_builtin(__builtin_amdgcn_exp2f)
#define EXP2F(x) __builtin_amdgcn_exp2f(x)
#else
#define EXP2F(x) exp2f(x)
#endif
#if __has_builtin(__builtin_amdgcn_rcpf)
#define RCPF(x) __builtin_amdgcn_rcpf(x)
#else
#define RCPF(x) (1.0f / (x))
#endif

#define LOG2E 1.4426950408889634f

__device__ __forceinline__ float fdot2(unsigned a, unsigned b, float c) {
    return __builtin_amdgcn_fdot2(__builtin_bit_cast(half2_t, a),
                                  __builtin_bit_cast(half2_t, b), c, false);
}

// Full-row 64-MAC dot: 8 weight quads vs 8 gathered-h quads, 4 chains.
__device__ __forceinline__ float dotrow(const uint4v* w, const uint4v* g, float init) {
    float a0 = init, a1 = 0.f, a2 = 0.f, a3 = 0.f;
    #pragma unroll
    for (int q = 0; q < 8; ++q) {
        a0 = fdot2(w[q][0], g[q][0], a0);
        a1 = fdot2(w[q][1], g[q][1], a1);
        a2 = fdot2(w[q][2], g[q][2], a2);
        a3 = fdot2(w[q][3], g[q][3], a3);
    }
    return (a0 + a1) + (a2 + a3);
}

__device__ __forceinline__ uint4v pack8(float4 a, float4 b, float s) {
    half2_t h0{(_Float16)(a.x * s), (_Float16)(a.y * s)};
    half2_t h1{(_Float16)(a.z * s), (_Float16)(a.w * s)};
    half2_t h2{(_Float16)(b.x * s), (_Float16)(b.y * s)};
    half2_t h3{(_Float16)(b.z * s), (_Float16)(b.w * s)};
    uint4v q;
    q[0] = __builtin_bit_cast(unsigned, h0);
    q[1] = __builtin_bit_cast(unsigned, h1);
    q[2] = __builtin_bit_cast(unsigned, h2);
    q[3] = __builtin_bit_cast(unsigned, h3);
    return q;
}

// One 64-float weight row -> 8 packed quads, exp2-space prescaled.
__device__ __forceinline__ void cvt8(const float* __restrict__ Wp, float s, uint4v* dst) {
    const float4* p = reinterpret_cast<const float4*>(Wp);
    #pragma unroll
    for (int k = 0; k < 8; ++k) dst[k] = pack8(p[2 * k], p[2 * k + 1], s);
}

__device__ __forceinline__ int ldf(int* f) {
    return __hip_atomic_load(f, __ATOMIC_RELAXED, __HIP_MEMORY_SCOPE_WORKGROUP);
}

// ROUND 17 = ROUND 15 (977 us best: WD=8, full unroll, SIMD-balanced roles)
// with the per-phase __syncthreads replaced by POINT-TO-POINT FLAG SYNC.
// R15 idle ~225 cyc/step was the global rendezvous; the true dependency
// graph is a depth-2-buffered pipeline C0 -> P1 -> C1 -> P2 -> C2.
// flags[w] = phases completed by wave w. At phase ph each wave waits only
// on the partners whose phase-(ph-1) output it reads or whose reads it is
// about to overwrite (RAW + WAR, both directions verified):
//   wv0 (C0)     waits {3,4,5,6}   (they read h0ring[par] last phase)
//   wv1 (C1)     waits {3,4,5,6,7} (p1 RAW; wv3/wv7 read h1ring[par])
//   wv2 (C2)     waits {3,7}       (p2 RAW)
//   wv3          waits {0,1,2}     (h0/h1 RAW; p1/p2 WAR vs C1/C2)
//   wv4/5/6      waits {0,1}       (h0 RAW; p1 WAR vs C1)
//   wv7          waits {1,2}       (h1 RAW; p2 WAR vs C2)
// Deadlock-free: every wait references only phase-(ph-1) completion and
// every wave publishes its flag every phase unconditionally.
// Roles (R15): wv0/1/2 = C0/C1/C2 (4 whh rows each, in-lane gates, scalar
// cell); wv4/5/6 = wih1_{i,f,g}; wv3 = wih1_o + wih2_i; wv7 = wih2_{f,g,o}.
// All four SIMDs = 5120 dot-cyc per phase (balanced).
__global__ __launch_bounds__(512)
__attribute__((amdgpu_waves_per_eu(2, 2)))
void lstm3_fused(
    const float* __restrict__ x,
    const float* __restrict__ Wih0, const float* __restrict__ Whh0,
    const float* __restrict__ bih0, const float* __restrict__ bhh0,
    const float* __restrict__ Wih1, const float* __restrict__ Whh1,
    const float* __restrict__ bih1, const float* __restrict__ bhh1,
    const float* __restrict__ Wih2, const float* __restrict__ Whh2,
    const float* __restrict__ bih2, const float* __restrict__ bhh2,
    const float* __restrict__ fcW,  const float* __restrict__ fcb,
    float* __restrict__ out)
{
    const int b   = blockIdx.x;
    const int tid = threadIdx.x;
    const int wv  = tid >> 6;          // 0..7 (wave-uniform role)
    const int L   = tid & 63;          // owned h-index / row-lane

    __shared__ __align__(16) _Float16 h0ring[2 * WD][HID];
    __shared__ __align__(16) _Float16 h1ring[2 * WD][HID];
    __shared__ __align__(16) _Float16 h2ring[2][HID];
    __shared__ float p1buf[2][WD][4][HID];
    __shared__ float p2buf[2][WD][4][HID];
    __shared__ __align__(16) float xs[T_LEN];
    __shared__ int flags[8];

    // Stage x[b,0,:]; zero rings and flags.
    {
        const float4* xg4 = reinterpret_cast<const float4*>(x + b * T_LEN);
        reinterpret_cast<float4*>(xs)[tid] = xg4[tid];
        reinterpret_cast<unsigned*>(h0ring)[tid & 511] = 0u;
        reinterpret_cast<unsigned*>(h1ring)[tid & 511] = 0u;
        if (tid < 64) reinterpret_cast<unsigned*>(h2ring)[tid] = 0u;
        if (tid < 8) flags[tid] = 0;
    }

    const float sI = -LOG2E, sF = -LOG2E, sG = -2.f * LOG2E, sO = -LOG2E;
    const float scl[4] = {sI, sF, sG, sO};

    uint4v w[4][8];                    // C: 4 whh rows; wv3: 2; wv7: 3
    float bias4[4] = {0.f, 0.f, 0.f, 0.f};
    float wx4[4]   = {0.f, 0.f, 0.f, 0.f};

    if (wv < 3) {                      // C_l: whh_l all 4 gate rows
        const float* Wh = (wv == 0) ? Whh0 : (wv == 1) ? Whh1 : Whh2;
        const float* bi = (wv == 0) ? bih0 : (wv == 1) ? bih1 : bih2;
        const float* bh = (wv == 0) ? bhh0 : (wv == 1) ? bhh1 : bhh2;
        #pragma unroll
        for (int c = 0; c < 4; ++c) {
            cvt8(Wh + (c * 64 + L) * 64, scl[c], w[c]);
            bias4[c] = (bi[c * 64 + L] + bh[c * 64 + L]) * scl[c];
        }
        if (wv == 0) {
            #pragma unroll
            for (int c = 0; c < 4; ++c) wx4[c] = Wih0[c * 64 + L] * scl[c];
        }
    } else if (wv == 4) {              // P: wih1_i
        cvt8(Wih1 + (  0 + L) * 64, sI, w[0]);
    } else if (wv == 5) {              // P: wih1_f
        cvt8(Wih1 + ( 64 + L) * 64, sF, w[0]);
    } else if (wv == 6) {              // P: wih1_g
        cvt8(Wih1 + (128 + L) * 64, sG, w[0]);
    } else if (wv == 3) {              // P: wih1_o + wih2_i
        cvt8(Wih1 + (192 + L) * 64, sO, w[0]);
        cvt8(Wih2 + (  0 + L) * 64, sI, w[1]);
    } else {                           // wv == 7: wih2_{f,g,o}
        cvt8(Wih2 + ( 64 + L) * 64, sF, w[0]);
        cvt8(Wih2 + (128 + L) * 64, sG, w[1]);
        cvt8(Wih2 + (192 + L) * 64, sO, w[2]);
    }

    float cst = 0.f;                   // cell state (C waves, lane-local)
    __syncthreads();                   // staging + flags=0 visible

    for (int ph = 0; ph < NPH; ++ph) {
        const int par = ph & 1;

        // ---- dependency wait (replaces __syncthreads) ----
        {
            bool ok;
            do {
                if (wv == 0)
                    ok = (ldf(&flags[3]) >= ph) & (ldf(&flags[4]) >= ph)
                       & (ldf(&flags[5]) >= ph) & (ldf(&flags[6]) >= ph);
                else if (wv == 1)
                    ok = (ldf(&flags[3]) >= ph) & (ldf(&flags[4]) >= ph)
                       & (ldf(&flags[5]) >= ph) & (ldf(&flags[6]) >= ph)
                       & (ldf(&flags[7]) >= ph);
                else if (wv == 2)
                    ok = (ldf(&flags[3]) >= ph) & (ldf(&flags[7]) >= ph);
                else if (wv == 3)
                    ok = (ldf(&flags[0]) >= ph) & (ldf(&flags[1]) >= ph)
                       & (ldf(&flags[2]) >= ph);
                else if (wv == 7)
                    ok = (ldf(&flags[1]) >= ph) & (ldf(&flags[2]) >= ph);
                else
                    ok = (ldf(&flags[0]) >= ph) & (ldf(&flags[1]) >= ph);
                if (!ok) __builtin_amdgcn_s_sleep(1);
            } while (!ok);
            __builtin_amdgcn_fence(__ATOMIC_ACQUIRE, "workgroup");
        }

        if (wv == 0) {
            if (ph < NWIN) {           // h0 window ph
                _Float16* cur = &h0ring[par * WD][0];
                const _Float16* prv = &h0ring[(par ^ 1) * WD][0];
                const int tb = ph * WD;
                #pragma unroll
                for (int j = 0; j < WD; ++j) {
                    const uint4v* hp = reinterpret_cast<const uint4v*>(
                        (j == 0) ? (prv + (WD - 1) * HID) : (cur + (j - 1) * HID));
                    uint4v g[8];
                    #pragma unroll
                    for (int k = 0; k < 8; ++k) g[k] = hp[k];
                    float xv = xs[tb + j];
                    float d0 = dotrow(w[0], g, fmaf(wx4[0], xv, bias4[0]));
                    float d1 = dotrow(w[1], g, fmaf(wx4[1], xv, bias4[1]));
                    float d2 = dotrow(w[2], g, fmaf(wx4[2], xv, bias4[2]));
                    float d3 = dotrow(w[3], g, fmaf(wx4[3], xv, bias4[3]));
                    float ai = RCPF(1.f + EXP2F(d0));
                    float af = RCPF(1.f + EXP2F(d1));
                    float ag = fmaf(2.f, RCPF(1.f + EXP2F(d2)), -1.f);
                    float ao = RCPF(1.f + EXP2F(d3));
                    cst = fmaf(af, cst, ai * ag);
                    float tc = fmaf(2.f, RCPF(1.f + EXP2F(-2.f * LOG2E * cst)), -1.f);
                    cur[j * HID + L] = (_Float16)(ao * tc);
                }
            }
        } else if (wv == 1) {
            if (ph >= 2 && ph < NWIN + 2) {    // h1 window ph-2
                _Float16* cur = &h1ring[par * WD][0];
                const _Float16* prv = &h1ring[(par ^ 1) * WD][0];
                const float (*pb)[4][HID] = p1buf[par];
                #pragma unroll
                for (int j = 0; j < WD; ++j) {
                    const uint4v* hp = reinterpret_cast<const uint4v*>(
                        (j == 0) ? (prv + (WD - 1) * HID) : (cur + (j - 1) * HID));
                    uint4v g[8];
                    #pragma unroll
                    for (int k = 0; k < 8; ++k) g[k] = hp[k];
                    float d0 = dotrow(w[0], g, bias4[0] + pb[j][0][L]);
                    float d1 = dotrow(w[1], g, bias4[1] + pb[j][1][L]);
                    float d2 = dotrow(w[2], g, bias4[2] + pb[j][2][L]);
                    float d3 = dotrow(w[3], g, bias4[3] + pb[j][3][L]);
                    float ai = RCPF(1.f + EXP2F(d0));
                    float af = RCPF(1.f + EXP2F(d1));
                    float ag = fmaf(2.f, RCPF(1.f + EXP2F(d2)), -1.f);
                    float ao = RCPF(1.f + EXP2F(d3));
                    cst = fmaf(af, cst, ai * ag);
                    float tc = fmaf(2.f, RCPF(1.f + EXP2F(-2.f * LOG2E * cst)), -1.f);
                    cur[j * HID + L] = (_Float16)(ao * tc);
                }
            }
        } else if (wv == 2) {
            if (ph >= 4) {                     // h2 window ph-4
                const float (*pb)[4][HID] = p2buf[par];
                #pragma unroll
                for (int j = 0; j < WD; ++j) {
                    const uint4v* hp = reinterpret_cast<const uint4v*>(
                        &h2ring[(j & 1) ^ 1][0]);
                    uint4v g[8];
                    #pragma unroll
                    for (int k = 0; k < 8; ++k) g[k] = hp[k];
                    float d0 = dotrow(w[0], g, bias4[0] + pb[j][0][L]);
                    float d1 = dotrow(w[1], g, bias4[1] + pb[j][1][L]);
                    float d2 = dotrow(w[2], g, bias4[2] + pb[j][2][L]);
                    float d3 = dotrow(w[3], g, bias4[3] + pb[j][3][L]);
                    float ai = RCPF(1.f + EXP2F(d0));
                    float af = RCPF(1.f + EXP2F(d1));
                    float ag = fmaf(2.f, RCPF(1.f + EXP2F(d2)), -1.f);
                    float ao = RCPF(1.f + EXP2F(d3));
                    cst = fmaf(af, cst, ai * ag);
                    float tc = fmaf(2.f, RCPF(1.f + EXP2F(-2.f * LOG2E * cst)), -1.f);
                    h2ring[j & 1][L] = (_Float16)(ao * tc);
                }
            }
        } else {
            const bool p1act = (ph >= 1 && ph < NWIN + 1);
            const bool p2act = (ph >= 3 && ph < NWIN + 3);
            if (wv == 4 || wv == 5 || wv == 6) {
                if (p1act) {                   // one wih1 row vs h0 window ph-1
                    const _Float16* hw = &h0ring[(par ^ 1) * WD][0];
                    float (*po)[4][HID] = p1buf[par ^ 1];
                    const int c0 = wv - 4;
                    #pragma unroll
                    for (int j = 0; j < WD; ++j) {
                        const uint4v* hp = reinterpret_cast<const uint4v*>(hw + j * HID);
                        uint4v g[8];
                        #pragma unroll
                        for (int k = 0; k < 8; ++k) g[k] = hp[k];
                        po[j][c0][L] = dotrow(w[0], g, 0.f);
                    }
                }
            } else if (wv == 3) {
                if (p1act) {                   // wih1_o vs h0 window ph-1
                    const _Float16* hw = &h0ring[(par ^ 1) * WD][0];
                    float (*po)[4][HID] = p1buf[par ^ 1];
                    #pragma unroll
                    for (int j = 0; j < WD; ++j) {
                        const uint4v* hp = reinterpret_cast<const uint4v*>(hw + j * HID);
                        uint4v g[8];
                        #pragma unroll
                        for (int k = 0; k < 8; ++k) g[k] = hp[k];
                        po[j][3][L] = dotrow(w[0], g, 0.f);
                    }
                }
                if (p2act) {                   // wih2_i vs h1 window ph-3
                    const _Float16* hw = &h1ring[(par ^ 1) * WD][0];
                    float (*po)[4][HID] = p2buf[par ^ 1];
                    #pragma unroll
                    for (int j = 0; j < WD; ++j) {
                        const uint4v* hp = reinterpret_cast<const uint4v*>(hw + j * HID);
                        uint4v g[8];
                        #pragma unroll
                        for (int k = 0; k < 8; ++k) g[k] = hp[k];
                        po[j][0][L] = dotrow(w[1], g, 0.f);
                    }
                }
            } else {                           // wv == 7: wih2_{f,g,o}
                if (p2act) {
                    const _Float16* hw = &h1ring[(par ^ 1) * WD][0];
                    float (*po)[4][HID] = p2buf[par ^ 1];
                    #pragma unroll
                    for (int j = 0; j < WD; ++j) {
                        const uint4v* hp = reinterpret_cast<const uint4v*>(hw + j * HID);
                        uint4v g[8];
                        #pragma unroll
                        for (int k = 0; k < 8; ++k) g[k] = hp[k];
                        po[j][1][L] = dotrow(w[0], g, 0.f);
                        po[j][2][L] = dotrow(w[1], g, 0.f);
                        po[j][3][L] = dotrow(w[2], g, 0.f);
                    }
                }
            }
        }

        // ---- publish phase completion (release) ----
        __builtin_amdgcn_fence(__ATOMIC_RELEASE, "workgroup");
        if ((tid & 63) == 0)
            __hip_atomic_store(&flags[wv], ph + 1, __ATOMIC_RELAXED,
                               __HIP_MEMORY_SCOPE_WORKGROUP);
    }

    __syncthreads();   // final: h2ring visible to FC waves

    // Final FC (f32): h2[2047] -> window step 7 -> slot 7&1 = 1.
    if (tid < EMB) {
        float acc = fcb[tid];
        const _Float16* hf = &h2ring[1][0];
        const float4* W4 = reinterpret_cast<const float4*>(fcW + tid * HID);
        #pragma unroll
        for (int k = 0; k < 16; ++k) {
            float4 wv4 = W4[k];
            acc = fmaf(wv4.x, (float)hf[4 * k + 0], acc);
            acc = fmaf(wv4.y, (float)hf[4 * k + 1], acc);
            acc = fmaf(wv4.z, (float)hf[4 * k + 2], acc);
            acc = fmaf(wv4.w, (float)hf[4 * k + 3], acc);
        }
        out[b * EMB + tid] = acc;
    }
}

extern "C" void kernel_launch(void* const* d_in, const int* in_sizes, int n_in,
                              void* d_out, int out_size, void* d_ws, size_t ws_size,
                              hipStream_t stream) {
    const float* x    = (const float*)d_in[0];
    const float* Wih0 = (const float*)d_in[1];
    const float* Whh0 = (const float*)d_in[2];
    const float* bih0 = (const float*)d_in[3];
    const float* bhh0 = (const float*)d_in[4];
    const float* Wih1 = (const float*)d_in[5];
    const float* Whh1 = (const float*)d_in[6];
    const float* bih1 = (const float*)d_in[7];
    const float* bhh1 = (const float*)d_in[8];
    const float* Wih2 = (const float*)d_in[9];
    const float* Whh2 = (const float*)d_in[10];
    const float* bih2 = (const float*)d_in[11];
    const float* bhh2 = (const float*)d_in[12];
    const float* fcW  = (const float*)d_in[13];
    const float* fcb  = (const float*)d_in[14];
    float* out = (float*)d_out;

    lstm3_fused<<<dim3(256), dim3(512), 0, stream>>>(
        x, Wih0, Whh0, bih0, bhh0,
        Wih1, Whh1, bih1, bhh1,
        Wih2, Whh2, bih2, bhh2,
        fcW, fcb, out);
}